// Round 2
// baseline (469.725 us; speedup 1.0000x reference)
//
#include <hip/hip_runtime.h>

typedef short bf16x8 __attribute__((ext_vector_type(8)));
typedef float f32x4 __attribute__((ext_vector_type(4)));

__device__ __forceinline__ unsigned short f2bf(float f) {
  unsigned x = __float_as_uint(f);
  return (unsigned short)((x + 0x7fffu + ((x >> 16) & 1u)) >> 16);  // RNE
}

// ---------------------------------------------------------------------------
// Tile images: every tile is 18432 B = 9216 u16, covering 128 rows x 64 k.
//   A-tiles (X, H):  elem (r, k) at  r*72 + k                      (pad 64->72)
//   W-tiles:         elem (n, k) at  n*72 + (k ^ (((n>>3)&7)<<3))  (pad + XOR)
// These are the EXACT LDS layouts the GEMM uses, so GEMM staging is a
// verbatim linear copy (coalesced global int4 -> linear ds_write_b128).
// ---------------------------------------------------------------------------

// x [256][4096] f32 -> Ximg tiles [mt<2][kt<64]
__global__ __launch_bounds__(256)
void pack_x(const float* __restrict__ x, unsigned short* __restrict__ img) {
  const int i = (blockIdx.x * 256 + threadIdx.x) * 8;   // 1M elems, 512 blocks
  const int m = i >> 12, k = i & 4095;
  float q[8];
  *(float4*)(q)     = *(const float4*)(x + i);
  *(float4*)(q + 4) = *(const float4*)(x + i + 4);
  union { unsigned short u[8]; int4 v; } t;
#pragma unroll
  for (int j = 0; j < 8; ++j) t.u[j] = f2bf(q[j]);
  const size_t o = (size_t)((m >> 7) * 64 + (k >> 6)) * 9216 + (m & 127) * 72 + (k & 63);
  *(int4*)(img + o) = t.v;
}

// W1 [4096][8192] f32 -> panel p (128 cols), live tiles kt<=p.
// Panel tile base: T1(p) = p(p+1)/2.
__global__ __launch_bounds__(256)
void pack_w1(const float* __restrict__ W, unsigned short* __restrict__ img) {
  const int p = blockIdx.x;          // 0..63
  const int kt = blockIdx.y;         // 0..63
  if (kt > p) return;                // live k < (p+1)*64
  __shared__ unsigned short S[9216];
  const int r  = threadIdx.x >> 2;         // 0..63 (k within tile)
  const int c0 = (threadIdx.x & 3) * 32;   // col group
  const float* src = W + (size_t)(kt * 64 + r) * 8192 + p * 128 + c0;
  float q[32];
#pragma unroll
  for (int j = 0; j < 8; ++j) *(float4*)(q + j * 4) = *(const float4*)(src + j * 4);
#pragma unroll
  for (int j = 0; j < 32; ++j) {
    const int n = c0 + j;
    S[n * 72 + (r ^ (((n >> 3) & 7) << 3))] = f2bf(q[j]);
  }
  __syncthreads();
  unsigned short* dst = img + (size_t)(p * (p + 1) / 2 + kt) * 9216;
#pragma unroll
  for (int i = 0; i < 9; ++i) {
    const int s = (threadIdx.x + i * 256) * 4;          // 2304 int2 slots
    *(int2*)(dst + s) = *(const int2*)(S + s);
  }
}

// W2 [8192][4096] f32 -> panel p (128 cols = mask col-blocks {2p,2p+1}),
// live tiles kt < 4p+4; left half (c<64) zeroed for k >= (2p+1)*128.
// Panel tile base: T2(p) = 2p(p+1).
__global__ __launch_bounds__(256)
void pack_w2(const float* __restrict__ W, unsigned short* __restrict__ img) {
  const int p = blockIdx.x;          // 0..31
  const int kt = blockIdx.y;         // 0..127
  if (kt >= 4 * p + 4) return;
  __shared__ unsigned short S[9216];
  const int r  = threadIdx.x >> 2;
  const int c0 = (threadIdx.x & 3) * 32;
  const int k  = kt * 64 + r;
  const int lk = (2 * p + 1 + (c0 >= 64 ? 1 : 0)) * 128;  // live limit for this half
  const float* src = W + (size_t)k * 4096 + p * 128 + c0;
  float q[32];
#pragma unroll
  for (int j = 0; j < 8; ++j) *(float4*)(q + j * 4) = *(const float4*)(src + j * 4);
  const float sc = (k < lk) ? 1.f : 0.f;
#pragma unroll
  for (int j = 0; j < 32; ++j) {
    const int n = c0 + j;
    S[n * 72 + (r ^ (((n >> 3) & 7) << 3))] = f2bf(q[j] * sc);
  }
  __syncthreads();
  unsigned short* dst = img + (size_t)(2 * p * (p + 1) + kt) * 9216;
#pragma unroll
  for (int i = 0; i < 9; ++i) {
    const int s = (threadIdx.x + i * 256) * 4;
    *(int2*)(dst + s) = *(const int2*)(S + s);
  }
}

// out[m][n] = b2[n]  (GEMM2 atomically accumulates on top)
__global__ __launch_bounds__(256)
void init_bias(const float* __restrict__ b, float* __restrict__ out) {
  int i = (blockIdx.x * 256 + threadIdx.x) * 4;
  *(float4*)(out + i) = *(const float4*)(b + (i & 4095));
}

// Himg = packed bf16 tiles of relu(H_acc + b1);  H_acc [256][8192] f32
__global__ __launch_bounds__(256)
void bias_relu_pack(const float* __restrict__ h, const float* __restrict__ b1,
                    unsigned short* __restrict__ img) {
  const int i = (blockIdx.x * 256 + threadIdx.x) * 8;   // 2M elems, 1024 blocks
  const int m = i >> 13, k = i & 8191;
  float q[8];
  *(float4*)(q)     = *(const float4*)(h + i);
  *(float4*)(q + 4) = *(const float4*)(h + i + 4);
  union { unsigned short u[8]; int4 v; } t;
#pragma unroll
  for (int j = 0; j < 8; ++j)
    t.u[j] = f2bf(fmaxf(q[j] + b1[k + j], 0.f));
  const size_t o = (size_t)((m >> 7) * 128 + (k >> 6)) * 9216 + (m & 127) * 72 + (k & 63);
  *(int4*)(img + o) = t.v;
}

// ---------------------------------------------------------------------------
// GEMM on packed images. BM=128, BN=128, BK=64; 256 thr = 4 waves (2x2), each
// wave owns a 64x64 quadrant (acc 4x4 frags). Staging = linear copy of two
// 18 KB tiles (waves 0,1 -> Xs; waves 2,3 -> Ws), prefetched one iter ahead.
// Panel p: nIter = p*IM + IA live BK-tiles, tile base = IM*p(p-1)/2 + IA*p.
// Split-K over KS z-blocks; fp32 atomic accumulate into out (pre-initialized).
// blockIdx.x reversed so heavy (high-p) tiles dispatch first.
// ---------------------------------------------------------------------------
template<int IM, int IA, int KT, int KS>
__global__ __launch_bounds__(256, 3)
void gemm_img(const unsigned short* __restrict__ Aimg,
              const unsigned short* __restrict__ Wimg,
              float* __restrict__ out, int N) {
  __shared__ unsigned short Xs[9216];   // A-tile image
  __shared__ unsigned short Ws[9216];   // W-tile image

  const int p  = (int)gridDim.x - 1 - (int)blockIdx.x;
  const int mt = blockIdx.y;
  const int nIter = p * IM + IA;
  const int i0 = (int)blockIdx.z * nIter / KS;
  const int i1 = ((int)blockIdx.z + 1) * nIter / KS;
  if (i0 == i1) return;                 // uniform exit before any barrier

  const size_t tb = (size_t)IM * ((size_t)p * (p - 1) / 2) + (size_t)IA * p;
  const char* Wp = (const char*)Wimg + tb * 18432;
  const char* Ap = (const char*)Aimg + (size_t)mt * KT * 18432;

  const int tid = threadIdx.x, lane = tid & 63, wave = tid >> 6;
  const int l15 = lane & 15, quad = lane >> 4;
  const int wm0 = (wave & 1) * 64, wn0 = (wave >> 1) * 64;

  // staging assignment: per-wave 9 KB linear chunk
  const char* gsrc0 = (wave < 2) ? Ap : Wp;
  const int   half  = (wave & 1) * 9216;
  char*       ldst  = ((wave < 2) ? (char*)Xs : (char*)Ws) + half;
  const int   loff  = lane * 16;

  int4 st[9];
  auto loadG = [&](int kt) {
    const char* g = gsrc0 + (size_t)kt * 18432 + half + loff;
#pragma unroll
    for (int j = 0; j < 9; ++j) st[j] = *(const int4*)(g + j * 1024);
  };
  auto storeL = [&]() {
#pragma unroll
    for (int j = 0; j < 9; ++j) *(int4*)(ldst + loff + j * 1024) = st[j];
  };

  f32x4 acc[4][4];
#pragma unroll
  for (int mi = 0; mi < 4; ++mi)
#pragma unroll
    for (int ni = 0; ni < 4; ++ni)
      acc[mi][ni] = (f32x4){0.f, 0.f, 0.f, 0.f};

  loadG(i0);
  for (int kt = i0; kt < i1; ++kt) {
    __syncthreads();                    // prior tile's LDS reads done
    storeL();
    if (kt + 1 < i1) loadG(kt + 1);     // prefetch overlaps barrier+MFMA
    __syncthreads();                    // stores visible
#pragma unroll
    for (int kk = 0; kk < 64; kk += 32) {
      bf16x8 af[4], bfr[4];
#pragma unroll
      for (int mi = 0; mi < 4; ++mi)
        af[mi] = *(const bf16x8*)(&Xs[(wm0 + mi * 16 + l15) * 72 + kk + quad * 8]);
#pragma unroll
      for (int ni = 0; ni < 4; ++ni) {
        const int n = wn0 + ni * 16 + l15;
        bfr[ni] = *(const bf16x8*)(&Ws[n * 72 + ((kk + quad * 8) ^ (((n >> 3) & 7) << 3))]);
      }
#pragma unroll
      for (int mi = 0; mi < 4; ++mi)
#pragma unroll
        for (int ni = 0; ni < 4; ++ni)
          acc[mi][ni] = __builtin_amdgcn_mfma_f32_16x16x32_bf16(
              af[mi], bfr[ni], acc[mi][ni], 0, 0, 0);
    }
  }

  // epilogue: C/D layout col=lane&15, row=quad*4+reg; fp32 atomic accumulate
  const int m0 = mt * 128, n0 = p * 128;
#pragma unroll
  for (int mi = 0; mi < 4; ++mi)
#pragma unroll
    for (int ni = 0; ni < 4; ++ni) {
      const int n_out = n0 + wn0 + ni * 16 + l15;
#pragma unroll
      for (int r = 0; r < 4; ++r) {
        const int m_out = m0 + wm0 + mi * 16 + quad * 4 + r;
        atomicAdd(&out[(size_t)m_out * N + n_out], acc[mi][ni][r]);
      }
    }
}

extern "C" void kernel_launch(void* const* d_in, const int* in_sizes, int n_in,
                              void* d_out, int out_size, void* d_ws, size_t ws_size,
                              hipStream_t stream) {
  const float* x  = (const float*)d_in[0];  // [256,64,64] fp32
  const float* W1 = (const float*)d_in[1];  // [4096,8192] fp32
  const float* b1 = (const float*)d_in[2];  // [8192] fp32
  const float* W2 = (const float*)d_in[3];  // [8192,4096] fp32
  const float* b2 = (const float*)d_in[4];  // [4096] fp32
  // dims hardcoded: B=256, S=64, I=64, H=128, O=64

  // workspace layout (~93 MB), all 256B-aligned:
  char* ws = (char*)d_ws;
  unsigned short* Ximg  = (unsigned short*)ws;                    //  2,359,296 B
  unsigned short* W1img = (unsigned short*)(ws + 2359296);        // 38,338,560 B (2080 tiles)
  unsigned short* Himg  = (unsigned short*)(ws + 2359296 + 38338560);               // 4,718,592 B
  unsigned short* W2img = (unsigned short*)(ws + 2359296 + 38338560 + 4718592);     // 38,928,384 B (2112 tiles)
  float*          H_acc = (float*)(ws + 2359296 + 38338560 + 4718592 + 38928384);   // 8,388,608 B
  float* out = (float*)d_out;               // [256,4096] fp32

  pack_x <<<dim3(512),      256, 0, stream>>>(x,  Ximg);
  pack_w1<<<dim3(64, 64),   256, 0, stream>>>(W1, W1img);
  pack_w2<<<dim3(32, 128),  256, 0, stream>>>(W2, W2img);
  hipMemsetAsync(H_acc, 0, (size_t)256 * 8192 * sizeof(float), stream);
  init_bias<<<dim3(1024),   256, 0, stream>>>(b2, out);

  // GEMM1: Ximg @ W1img -> H_acc (atomic).  nIter = p+1, KS=8.
  gemm_img<1, 1, 64, 8><<<dim3(64, 2, 8), 256, 0, stream>>>(
      Ximg, W1img, H_acc, 8192);

  // H -> packed bf16 tiles with bias+relu
  bias_relu_pack<<<dim3(1024), 256, 0, stream>>>(H_acc, b1, Himg);

  // GEMM2: Himg @ W2img -> out (atomic, pre-filled b2).  nIter = 4p+4, KS=16.
  gemm_img<4, 4, 128, 16><<<dim3(32, 2, 16), 256, 0, stream>>>(
      Himg, W2img, out, 4096);
}